// Round 1
// baseline (488.029 us; speedup 1.0000x reference)
//
#include <hip/hip_runtime.h>
#include <hip/hip_bf16.h>

// ZorroPP: the [C,M] sketch never needs materializing.
// mu_hat[c] = g[c]/M * ( exp(-t/64)*rowsum_sketch[c]
//                        + (1/t)*g[c]*colsum_x[c]*len(h)
//                        + 0.01*rowsum_noise[c] )
// out = s*(x - mu_hat) @ W + b,  s = 1/((1+1e-6)*sqrt(0.375+1e-6))

#define BMT 64
#define BNT 64
#define BKT 16

__global__ __launch_bounds__(256) void zero_kernel(float* __restrict__ p, int n) {
    int i = blockIdx.x * 256 + threadIdx.x;
    if (i < n) p[i] = 0.0f;
}

// colsum[c] = sum_b x[b,c]; grid (C/256, B/64)
__global__ __launch_bounds__(256) void colsum_kernel(const float* __restrict__ x,
                                                     float* __restrict__ colsum,
                                                     int Cdim) {
    int c = blockIdx.x * 256 + threadIdx.x;
    int b0 = blockIdx.y * 64;
    float acc = 0.0f;
#pragma unroll 4
    for (int b = b0; b < b0 + 64; ++b)
        acc += x[(size_t)b * Cdim + c];
    atomicAdd(&colsum[c], acc);
}

// One block per channel c: fused rowsum of sketch_mu and noise -> mu_hat[c]
__global__ __launch_bounds__(256) void muhat_kernel(const float* __restrict__ sk,
                                                    const float* __restrict__ noise,
                                                    const float* __restrict__ g,
                                                    const float* __restrict__ colsum,
                                                    const int* __restrict__ t_ptr,
                                                    float* __restrict__ mu,
                                                    int Msk, float hcount) {
    int row = blockIdx.x;
    const float4* srow = reinterpret_cast<const float4*>(sk + (size_t)row * Msk);
    const float4* nrow = reinterpret_cast<const float4*>(noise + (size_t)row * Msk);
    int n4 = Msk >> 2;
    float ss = 0.0f, sn = 0.0f;
    for (int i = threadIdx.x; i < n4; i += 256) {
        float4 v = srow[i];
        float4 w = nrow[i];
        ss += (v.x + v.y) + (v.z + v.w);
        sn += (w.x + w.y) + (w.z + w.w);
    }
    // wave reduce (64 lanes)
#pragma unroll
    for (int off = 32; off > 0; off >>= 1) {
        ss += __shfl_down(ss, off);
        sn += __shfl_down(sn, off);
    }
    __shared__ float red[2][4];
    int wid = threadIdx.x >> 6;
    if ((threadIdx.x & 63) == 0) { red[0][wid] = ss; red[1][wid] = sn; }
    __syncthreads();
    if (threadIdx.x == 0) {
        ss = (red[0][0] + red[0][1]) + (red[0][2] + red[0][3]);
        sn = (red[1][0] + red[1][1]) + (red[1][2] + red[1][3]);
        float t = (float)(*t_ptr);
        float decay = expf(-t / 64.0f);      // 1 - lambda_t
        float kappa = 1.0f / t;
        float gc = g[row];
        mu[row] = gc / (float)Msk *
                  (decay * ss + kappa * gc * colsum[row] * hcount + 0.01f * sn);
    }
}

// out[i,k] = b[k]  (GEMM atomically accumulates on top)
__global__ __launch_bounds__(256) void init_out_kernel(const float* __restrict__ bias,
                                                       float* __restrict__ out,
                                                       int Kdim, int total) {
    int i = blockIdx.x * 256 + threadIdx.x;
    if (i < total) out[i] = bias[i % Kdim];
}

// out += s*(x - mu) @ W  over the z-th half of C. grid (B/64, ceil(K/64), 2)
__global__ __launch_bounds__(256) void gemm_kernel(const float* __restrict__ x,
                                                   const float* __restrict__ W,
                                                   const float* __restrict__ mu,
                                                   float* __restrict__ out,
                                                   int Cdim, int Kdim, float s) {
    __shared__ float As[BKT][BMT + 4];
    __shared__ float Bs[BKT][BNT + 4];

    int row0 = blockIdx.x * BMT;
    int col0 = blockIdx.y * BNT;
    int chalf = Cdim >> 1;
    int c_begin = blockIdx.z * chalf;
    int c_end = c_begin + chalf;

    int tid = threadIdx.x;
    int tx = tid & 15;
    int ty = tid >> 4;

    // A staging: one float4 of x per thread
    int a_r = tid >> 2;          // 0..63
    int a_c4 = (tid & 3) * 4;    // 0,4,8,12
    // B staging: one float4 of W per thread
    int b_r = tid >> 4;          // 0..15
    int b_c4 = (tid & 15) * 4;   // 0..60

    float acc[4][4] = {};

    for (int c0 = c_begin; c0 < c_end; c0 += BKT) {
        float4 av = *reinterpret_cast<const float4*>(
            &x[(size_t)(row0 + a_r) * Cdim + c0 + a_c4]);
        float4 mv = *reinterpret_cast<const float4*>(&mu[c0 + a_c4]);
        As[a_c4 + 0][a_r] = s * (av.x - mv.x);
        As[a_c4 + 1][a_r] = s * (av.y - mv.y);
        As[a_c4 + 2][a_r] = s * (av.z - mv.z);
        As[a_c4 + 3][a_r] = s * (av.w - mv.w);

        int col = col0 + b_c4;
        const float* wrow = &W[(size_t)(c0 + b_r) * Kdim];
        float4 bv;
        if (col + 3 < Kdim) {
            bv = *reinterpret_cast<const float4*>(&wrow[col]);
        } else {
            bv.x = (col + 0 < Kdim) ? wrow[col + 0] : 0.0f;
            bv.y = (col + 1 < Kdim) ? wrow[col + 1] : 0.0f;
            bv.z = (col + 2 < Kdim) ? wrow[col + 2] : 0.0f;
            bv.w = (col + 3 < Kdim) ? wrow[col + 3] : 0.0f;
        }
        *reinterpret_cast<float4*>(&Bs[b_r][b_c4]) = bv;

        __syncthreads();
#pragma unroll
        for (int kk = 0; kk < BKT; ++kk) {
            float4 a = *reinterpret_cast<const float4*>(&As[kk][ty * 4]);
            float4 b = *reinterpret_cast<const float4*>(&Bs[kk][tx * 4]);
            acc[0][0] += a.x * b.x; acc[0][1] += a.x * b.y;
            acc[0][2] += a.x * b.z; acc[0][3] += a.x * b.w;
            acc[1][0] += a.y * b.x; acc[1][1] += a.y * b.y;
            acc[1][2] += a.y * b.z; acc[1][3] += a.y * b.w;
            acc[2][0] += a.z * b.x; acc[2][1] += a.z * b.y;
            acc[2][2] += a.z * b.z; acc[2][3] += a.z * b.w;
            acc[3][0] += a.w * b.x; acc[3][1] += a.w * b.y;
            acc[3][2] += a.w * b.z; acc[3][3] += a.w * b.w;
        }
        __syncthreads();
    }

#pragma unroll
    for (int j = 0; j < 4; ++j) {
#pragma unroll
        for (int l = 0; l < 4; ++l) {
            int r = row0 + ty * 4 + j;
            int col = col0 + tx * 4 + l;
            if (col < Kdim)
                atomicAdd(&out[(size_t)r * Kdim + col], acc[j][l]);
        }
    }
}

extern "C" void kernel_launch(void* const* d_in, const int* in_sizes, int n_in,
                              void* d_out, int out_size, void* d_ws, size_t ws_size,
                              hipStream_t stream) {
    const float* x      = (const float*)d_in[0];   // [B, C]
    const float* sk     = (const float*)d_in[1];   // [C, M]
    const float* g      = (const float*)d_in[2];   // [C]
    const float* noise  = (const float*)d_in[3];   // [C, M]
    const float* W      = (const float*)d_in[4];   // [C, K]
    const float* bias   = (const float*)d_in[5];   // [K]
    // d_in[6] = h: only its LENGTH matters (sum of bincount == len(h))
    const int* t_ptr    = (const int*)d_in[7];

    int C    = in_sizes[2];
    int Bdim = in_sizes[0] / C;
    int Msk  = in_sizes[1] / C;
    int Kdim = in_sizes[5];
    float hcount = (float)in_sizes[6];

    float* colsum = (float*)d_ws;            // C floats
    float* mu     = colsum + C;              // C floats

    // combined Chebyshev scale: /(sqrt(1)+1e-6) then /sqrt(3/8+1e-6)
    float s = (float)(1.0 / ((1.0 + 1e-6) * sqrt(0.375 + 1e-6)));

    // 1) zero colsum
    zero_kernel<<<(C + 255) / 256, 256, 0, stream>>>(colsum, C);
    // 2) colsum of x
    {
        dim3 grid(C / 256, Bdim / 64);
        colsum_kernel<<<grid, 256, 0, stream>>>(x, colsum, C);
    }
    // 3) mu_hat (fused rowsums of sketch_mu and noise)
    muhat_kernel<<<C, 256, 0, stream>>>(sk, noise, g, colsum, t_ptr, mu, Msk, hcount);
    // 4) out = bias
    {
        int total = Bdim * Kdim;
        init_out_kernel<<<(total + 255) / 256, 256, 0, stream>>>(bias, (float*)d_out,
                                                                 Kdim, total);
    }
    // 5) out += s*(x-mu) @ W   (split-K = 2)
    {
        dim3 grid(Bdim / BMT, (Kdim + BNT - 1) / BNT, 2);
        gemm_kernel<<<grid, 256, 0, stream>>>(x, W, mu, (float*)d_out, C, Kdim, s);
    }
}

// Round 2
// 371.861 us; speedup vs baseline: 1.3124x; 1.3124x over previous
//
#include <hip/hip_runtime.h>
#include <hip/hip_bf16.h>

// ZorroPP: the [C,M] sketch never needs materializing.
// mu_hat[c] = g[c]/M * ( exp(-t/64)*rowsum_sketch[c]
//                        + (1/t)*g[c]*colsum_x[c]*len(h)
//                        + 0.01*rowsum_noise[c] )
// out = s*(x - mu_hat) @ W + b,  s = 1/((1+1e-6)*sqrt(0.375+1e-6))
//
// R2: GEMM was latency-bound (256 blocks = 1 wave/SIMD, Occupancy 11%).
// Now split-K=8 -> 1024 blocks (4 blocks/CU via __launch_bounds__(256,4)),
// BK=32, partials in d_ws + reduce kernel (atomic fallback if ws small).

#define SPLITK 8

// colsum[c] = sum_b x[b,c]; grid (C/256, B/32)
__global__ __launch_bounds__(256) void colsum_kernel(const float* __restrict__ x,
                                                     float* __restrict__ colsum,
                                                     int Cdim) {
    int c = blockIdx.x * 256 + threadIdx.x;
    int b0 = blockIdx.y * 32;
    float acc = 0.0f;
#pragma unroll 8
    for (int b = b0; b < b0 + 32; ++b)
        acc += x[(size_t)b * Cdim + c];
    atomicAdd(&colsum[c], acc);
}

// One block per channel c: fused rowsum of sketch_mu and noise -> mu_hat[c]
__global__ __launch_bounds__(256) void muhat_kernel(const float* __restrict__ sk,
                                                    const float* __restrict__ noise,
                                                    const float* __restrict__ g,
                                                    const float* __restrict__ colsum,
                                                    const int* __restrict__ t_ptr,
                                                    float* __restrict__ mu,
                                                    int Msk, float hcount) {
    int row = blockIdx.x;
    const float4* srow = reinterpret_cast<const float4*>(sk + (size_t)row * Msk);
    const float4* nrow = reinterpret_cast<const float4*>(noise + (size_t)row * Msk);
    int n4 = Msk >> 2;
    float ss = 0.0f, sn = 0.0f;
#pragma unroll 4
    for (int i = threadIdx.x; i < n4; i += 256) {
        float4 v = srow[i];
        float4 w = nrow[i];
        ss += (v.x + v.y) + (v.z + v.w);
        sn += (w.x + w.y) + (w.z + w.w);
    }
#pragma unroll
    for (int off = 32; off > 0; off >>= 1) {
        ss += __shfl_down(ss, off);
        sn += __shfl_down(sn, off);
    }
    __shared__ float red[2][4];
    int wid = threadIdx.x >> 6;
    if ((threadIdx.x & 63) == 0) { red[0][wid] = ss; red[1][wid] = sn; }
    __syncthreads();
    if (threadIdx.x == 0) {
        ss = (red[0][0] + red[0][1]) + (red[0][2] + red[0][3]);
        sn = (red[1][0] + red[1][1]) + (red[1][2] + red[1][3]);
        float t = (float)(*t_ptr);
        float decay = expf(-t / 64.0f);      // 1 - lambda_t
        float kappa = 1.0f / t;
        float gc = g[row];
        mu[row] = gc / (float)Msk *
                  (decay * ss + kappa * gc * colsum[row] * hcount + 0.01f * sn);
    }
}

// out[i,k] = b[k] (atomic-fallback path only)
__global__ __launch_bounds__(256) void init_out_kernel(const float* __restrict__ bias,
                                                       float* __restrict__ out,
                                                       int Kdim, int total) {
    int i = blockIdx.x * 256 + threadIdx.x;
    if (i < total) out[i] = bias[i % Kdim];
}

// s*(x - mu) @ W over the z-th C-chunk. grid (B/64, ceil(K/64), SPLITK).
// ATOMIC=false: write partial[z][row][col] to ws. ATOMIC=true: atomicAdd into out.
template <bool ATOMIC>
__global__ __launch_bounds__(256, 4) void gemm_kernel(const float* __restrict__ x,
                                                      const float* __restrict__ W,
                                                      const float* __restrict__ mu,
                                                      float* __restrict__ outp,
                                                      int Bdim, int Cdim, int Kdim,
                                                      int cchunk, float s) {
    __shared__ float As[32][68];   // [k][m]
    __shared__ float Bs[32][72];   // [k][n]

    int row0 = blockIdx.x * 64;
    int col0 = blockIdx.y * 64;
    int cbeg = blockIdx.z * cchunk;

    int tid = threadIdx.x;
    int tx = tid & 15;
    int ty = tid >> 4;
    int a_r = tid >> 2;            // 0..63
    int a_k = (tid & 3) * 4;       // 0,4,8,12  (+16 for second float4)
    int b_k = tid >> 3;            // 0..31
    int b_c = (tid & 7) * 8;       // 0,8,..,56 (+4 for second float4)

    float acc[4][4] = {};

    for (int c0 = cbeg; c0 < cbeg + cchunk; c0 += 32) {
        // --- global loads (issued early) ---
        const float* xr = &x[(size_t)(row0 + a_r) * Cdim + c0 + a_k];
        float4 a0 = *reinterpret_cast<const float4*>(xr);
        float4 a1 = *reinterpret_cast<const float4*>(xr + 16);
        float4 m0 = *reinterpret_cast<const float4*>(&mu[c0 + a_k]);
        float4 m1 = *reinterpret_cast<const float4*>(&mu[c0 + a_k + 16]);

        const float* wr = &W[(size_t)(c0 + b_k) * Kdim + col0 + b_c];
        int cb = col0 + b_c;
        float4 b0, b1;
        if (cb + 7 < Kdim) {
            b0 = *reinterpret_cast<const float4*>(wr);
            b1 = *reinterpret_cast<const float4*>(wr + 4);
        } else {
            b0.x = (cb + 0 < Kdim) ? wr[0] : 0.0f;
            b0.y = (cb + 1 < Kdim) ? wr[1] : 0.0f;
            b0.z = (cb + 2 < Kdim) ? wr[2] : 0.0f;
            b0.w = (cb + 3 < Kdim) ? wr[3] : 0.0f;
            b1.x = (cb + 4 < Kdim) ? wr[4] : 0.0f;
            b1.y = (cb + 5 < Kdim) ? wr[5] : 0.0f;
            b1.z = (cb + 6 < Kdim) ? wr[6] : 0.0f;
            b1.w = (cb + 7 < Kdim) ? wr[7] : 0.0f;
        }

        // --- stage to LDS ---
        As[a_k + 0][a_r] = s * (a0.x - m0.x);
        As[a_k + 1][a_r] = s * (a0.y - m0.y);
        As[a_k + 2][a_r] = s * (a0.z - m0.z);
        As[a_k + 3][a_r] = s * (a0.w - m0.w);
        As[a_k + 16][a_r] = s * (a1.x - m1.x);
        As[a_k + 17][a_r] = s * (a1.y - m1.y);
        As[a_k + 18][a_r] = s * (a1.z - m1.z);
        As[a_k + 19][a_r] = s * (a1.w - m1.w);
        *reinterpret_cast<float4*>(&Bs[b_k][b_c]) = b0;
        *reinterpret_cast<float4*>(&Bs[b_k][b_c + 4]) = b1;

        __syncthreads();
#pragma unroll
        for (int kk = 0; kk < 32; ++kk) {
            float4 a = *reinterpret_cast<const float4*>(&As[kk][ty * 4]);
            float4 b = *reinterpret_cast<const float4*>(&Bs[kk][tx * 4]);
            acc[0][0] += a.x * b.x; acc[0][1] += a.x * b.y;
            acc[0][2] += a.x * b.z; acc[0][3] += a.x * b.w;
            acc[1][0] += a.y * b.x; acc[1][1] += a.y * b.y;
            acc[1][2] += a.y * b.z; acc[1][3] += a.y * b.w;
            acc[2][0] += a.z * b.x; acc[2][1] += a.z * b.y;
            acc[2][2] += a.z * b.z; acc[2][3] += a.z * b.w;
            acc[3][0] += a.w * b.x; acc[3][1] += a.w * b.y;
            acc[3][2] += a.w * b.z; acc[3][3] += a.w * b.w;
        }
        __syncthreads();
    }

#pragma unroll
    for (int j = 0; j < 4; ++j) {
        int row = row0 + ty * 4 + j;
        int col = col0 + tx * 4;
        if (ATOMIC) {
#pragma unroll
            for (int l = 0; l < 4; ++l)
                if (col + l < Kdim)
                    atomicAdd(&outp[(size_t)row * Kdim + col + l], acc[j][l]);
        } else {
            float* pp = &outp[((size_t)blockIdx.z * Bdim + row) * Kdim + col];
            if (col + 3 < Kdim) {
                float4 v;
                v.x = acc[j][0]; v.y = acc[j][1]; v.z = acc[j][2]; v.w = acc[j][3];
                *reinterpret_cast<float4*>(pp) = v;
            } else {
#pragma unroll
                for (int l = 0; l < 4; ++l)
                    if (col + l < Kdim) pp[l] = acc[j][l];
            }
        }
    }
}

// out = bias + sum_z partial[z]; flat float4 over B*K
__global__ __launch_bounds__(256) void reduce_kernel(const float* __restrict__ part,
                                                     const float* __restrict__ bias,
                                                     float* __restrict__ out,
                                                     int total4, int Kdim, int perz) {
    int i = blockIdx.x * 256 + threadIdx.x;
    if (i >= total4) return;
    const float4* p4 = reinterpret_cast<const float4*>(part);
    float4 sum = p4[i];
#pragma unroll
    for (int z = 1; z < SPLITK; ++z) {
        float4 v = p4[(size_t)z * (perz >> 2) + i];
        sum.x += v.x; sum.y += v.y; sum.z += v.z; sum.w += v.w;
    }
    int e = i * 4;
    sum.x += bias[(e + 0) % Kdim];
    sum.y += bias[(e + 1) % Kdim];
    sum.z += bias[(e + 2) % Kdim];
    sum.w += bias[(e + 3) % Kdim];
    reinterpret_cast<float4*>(out)[i] = sum;
}

extern "C" void kernel_launch(void* const* d_in, const int* in_sizes, int n_in,
                              void* d_out, int out_size, void* d_ws, size_t ws_size,
                              hipStream_t stream) {
    const float* x      = (const float*)d_in[0];   // [B, C]
    const float* sk     = (const float*)d_in[1];   // [C, M]
    const float* g      = (const float*)d_in[2];   // [C]
    const float* noise  = (const float*)d_in[3];   // [C, M]
    const float* W      = (const float*)d_in[4];   // [C, K]
    const float* bias   = (const float*)d_in[5];   // [K]
    // d_in[6] = h: only its LENGTH matters (sum of bincount == len(h))
    const int* t_ptr    = (const int*)d_in[7];

    int C    = in_sizes[2];
    int Bdim = in_sizes[0] / C;
    int Msk  = in_sizes[1] / C;
    int Kdim = in_sizes[5];
    float hcount = (float)in_sizes[6];

    float* colsum = (float*)d_ws;            // C floats
    float* mu     = colsum + C;              // C floats
    float* part   = mu + C;                  // SPLITK*B*K floats (if it fits)

    size_t need = (size_t)(2 * C + SPLITK * Bdim * Kdim) * sizeof(float);
    bool use_partial = ws_size >= need;

    float s = (float)(1.0 / ((1.0 + 1e-6) * sqrt(0.375 + 1e-6)));
    int cchunk = C / SPLITK;

    // 1) colsum = 0 (memset node is graph-capturable)
    hipMemsetAsync(colsum, 0, C * sizeof(float), stream);
    // 2) colsum of x
    {
        dim3 grid(C / 256, Bdim / 32);
        colsum_kernel<<<grid, 256, 0, stream>>>(x, colsum, C);
    }
    // 3) mu_hat (fused rowsums of sketch_mu and noise)
    muhat_kernel<<<C, 256, 0, stream>>>(sk, noise, g, colsum, t_ptr, mu, Msk, hcount);
    // 4+5) GEMM (split-K) and combine
    dim3 ggrid(Bdim / 64, (Kdim + 63) / 64, SPLITK);
    if (use_partial) {
        gemm_kernel<false><<<ggrid, 256, 0, stream>>>(x, W, mu, part, Bdim, C, Kdim,
                                                      cchunk, s);
        int perz = Bdim * Kdim;
        int total4 = perz / 4;
        reduce_kernel<<<(total4 + 255) / 256, 256, 0, stream>>>(part, bias,
                                                                (float*)d_out,
                                                                total4, Kdim, perz);
    } else {
        int total = Bdim * Kdim;
        init_out_kernel<<<(total + 255) / 256, 256, 0, stream>>>(bias, (float*)d_out,
                                                                 Kdim, total);
        gemm_kernel<true><<<ggrid, 256, 0, stream>>>(x, W, mu, (float*)d_out, Bdim, C,
                                                     Kdim, cchunk, s);
    }
}